// Round 1
// baseline (461.481 us; speedup 1.0000x reference)
//
#include <hip/hip_runtime.h>
#include <hip/hip_bf16.h>
#include <cstdint>
#include <cstddef>

// Problem constants (from reference): M=2048, D=1024, I=2048, E=8, TOPK=2
#define DDIM  1024
#define IDIM  2048
#define NEXP  8
#define NPAIR 4096   // M * TOPK

typedef __attribute__((ext_vector_type(8))) short short8;   // 8 x bf16 (4 VGPRs)
typedef __attribute__((ext_vector_type(4))) float floatx4;  // MFMA accumulator

// ---- fp32x8 -> bf16x8 pack (RNE via packed cvt) ----
__device__ inline short8 pack8(float4 a, float4 b) {
    union { short8 s8; __hip_bfloat162 h[4]; } u;
    u.h[0] = __float22bfloat162_rn(float2{a.x, a.y});
    u.h[1] = __float22bfloat162_rn(float2{a.z, a.w});
    u.h[2] = __float22bfloat162_rn(float2{b.x, b.y});
    u.h[3] = __float22bfloat162_rn(float2{b.z, b.w});
    return u.s8;
}

// ============================================================================
// Kernel 1: routing. One block. Builds grouped slot list + per-expert offsets.
//   offs[e]..offs[e+1] is the slot range of expert e; slot_q[slot] = pair id q
//   (q = token*TOPK + k; token = q>>1 since TOPK=2).
// ============================================================================
__global__ void route_kernel(const int* __restrict__ eidx,
                             int* __restrict__ offs,
                             int* __restrict__ slot_q) {
    __shared__ int cnt[NEXP];
    __shared__ int cur[NEXP];
    const int t = threadIdx.x;
    if (t < NEXP) cnt[t] = 0;
    __syncthreads();
    for (int q = t; q < NPAIR; q += 256) atomicAdd(&cnt[eidx[q]], 1);
    __syncthreads();
    if (t == 0) {
        int s = 0;
        for (int e = 0; e < NEXP; e++) { offs[e] = s; cur[e] = s; s += cnt[e]; }
        offs[NEXP] = s;
    }
    __syncthreads();
    for (int q = t; q < NPAIR; q += 256) {
        int e = eidx[q];
        int pos = atomicAdd(&cur[e], 1);
        slot_q[pos] = q;
    }
}

// ============================================================================
// Kernel 2: grouped GEMM1 + fused SwiGLU.
//   For expert e, token-slots [mbase, mbase+128): h1 = x·w1^T, h3 = x·w3^T
//   over output cols [n0, n0+64); p = silu(h1)*h3 stored bf16 to pbuf.
//   Block: 256 thr (4 waves, 2x2). Tile: 128(M) x 64(N per half), BK=32.
// ============================================================================
__launch_bounds__(256)
__global__ void gemm1_swiglu(const float* __restrict__ x,
                             const float* __restrict__ w13,
                             const int* __restrict__ offs,
                             const int* __restrict__ slot_q,
                             unsigned short* __restrict__ pbuf) {
    const int e    = blockIdx.z;
    const int off0 = offs[e];
    const int ne   = offs[e + 1] - off0;
    const int mbase = blockIdx.y * 128;
    if (mbase >= ne) return;
    const int n0 = blockIdx.x * 64;

    // +8 pad (stride 40 shorts = 80B) -> 2-way bank conflicts on b128 reads (free)
    __shared__ __align__(16) short As[128][40];
    __shared__ __align__(16) short Bs[128][40];   // rows 0..63: w1, 64..127: w3

    const int t  = threadIdx.x;
    const int r  = t >> 1;   // staging row 0..127
    const int hf = t & 1;    // which 16-col half of BK=32

    // A: gathered token row (clamped for partial tiles; stores are guarded)
    int sl = mbase + r; if (sl > ne - 1) sl = ne - 1;
    const int q = slot_q[off0 + sl];
    const float* arow = x + (size_t)(q >> 1) * DDIM + hf * 16;
    // B: w1 rows [n0, n0+64) then w3 rows [IDIM+n0, IDIM+n0+64)
    const int wrow = (r < 64) ? (n0 + r) : (IDIM + n0 + (r - 64));
    const float* brow = w13 + (size_t)e * (2 * IDIM) * DDIM + (size_t)wrow * DDIM + hf * 16;

    const int lane = t & 63;
    const int wid  = t >> 6;
    const int wm   = wid >> 1;   // wave row 0..1 (64 slots each)
    const int wn   = wid & 1;    // wave col 0..1 (32 cols each)
    const int quad = lane >> 4;
    const int l16  = lane & 15;

    floatx4 acc1[4][2], acc3[4][2];
    #pragma unroll
    for (int i = 0; i < 4; i++)
        #pragma unroll
        for (int j = 0; j < 2; j++) {
            acc1[i][j] = floatx4{0.f, 0.f, 0.f, 0.f};
            acc3[i][j] = floatx4{0.f, 0.f, 0.f, 0.f};
        }

    for (int k0 = 0; k0 < DDIM; k0 += 32) {
        // ---- stage A,B (fp32 -> bf16) ----
        float4 a0 = *(const float4*)(arow + k0 + 0);
        float4 a1 = *(const float4*)(arow + k0 + 4);
        float4 a2 = *(const float4*)(arow + k0 + 8);
        float4 a3 = *(const float4*)(arow + k0 + 12);
        float4 b0 = *(const float4*)(brow + k0 + 0);
        float4 b1 = *(const float4*)(brow + k0 + 4);
        float4 b2 = *(const float4*)(brow + k0 + 8);
        float4 b3 = *(const float4*)(brow + k0 + 12);
        *(short8*)&As[r][hf * 16 + 0] = pack8(a0, a1);
        *(short8*)&As[r][hf * 16 + 8] = pack8(a2, a3);
        *(short8*)&Bs[r][hf * 16 + 0] = pack8(b0, b1);
        *(short8*)&Bs[r][hf * 16 + 8] = pack8(b2, b3);
        __syncthreads();

        // ---- fragments ----
        short8 af[4], b1f[2], b3f[2];
        #pragma unroll
        for (int mi = 0; mi < 4; mi++)
            af[mi] = *(short8*)&As[wm * 64 + mi * 16 + l16][quad * 8];
        #pragma unroll
        for (int ni = 0; ni < 2; ni++) {
            b1f[ni] = *(short8*)&Bs[wn * 32 + ni * 16 + l16][quad * 8];
            b3f[ni] = *(short8*)&Bs[64 + wn * 32 + ni * 16 + l16][quad * 8];
        }
        #pragma unroll
        for (int mi = 0; mi < 4; mi++)
            #pragma unroll
            for (int ni = 0; ni < 2; ni++) {
                acc1[mi][ni] = __builtin_amdgcn_mfma_f32_16x16x32_bf16(af[mi], b1f[ni], acc1[mi][ni], 0, 0, 0);
                acc3[mi][ni] = __builtin_amdgcn_mfma_f32_16x16x32_bf16(af[mi], b3f[ni], acc3[mi][ni], 0, 0, 0);
            }
        __syncthreads();
    }

    // ---- epilogue: p = silu(h1)*h3, bf16 store ----
    #pragma unroll
    for (int mi = 0; mi < 4; mi++) {
        #pragma unroll
        for (int ni = 0; ni < 2; ni++) {
            const int col = n0 + wn * 32 + ni * 16 + l16;
            #pragma unroll
            for (int rr = 0; rr < 4; rr++) {
                const int s2 = mbase + wm * 64 + mi * 16 + quad * 4 + rr;
                if (s2 < ne) {
                    float v1 = acc1[mi][ni][rr];
                    float v3 = acc3[mi][ni][rr];
                    float pv = v1 / (1.f + __expf(-v1)) * v3;
                    __hip_bfloat16 pb = __float2bfloat16(pv);
                    pbuf[(size_t)(off0 + s2) * IDIM + col] = *(unsigned short*)&pb;
                }
            }
        }
    }
}

// ============================================================================
// Kernel 3: grouped GEMM2 + scatter.  out[q, d] = sum_i p[slot, i] * w2[e, d, i]
//   Tile: 128(M) x 128(N), BK=32. A is bf16 (pbuf), B fp32 -> bf16.
// ============================================================================
__launch_bounds__(256)
__global__ void gemm2_scatter(const unsigned short* __restrict__ pbuf,
                              const float* __restrict__ w2,
                              const int* __restrict__ offs,
                              const int* __restrict__ slot_q,
                              float* __restrict__ out) {
    const int e    = blockIdx.z;
    const int off0 = offs[e];
    const int ne   = offs[e + 1] - off0;
    const int mbase = blockIdx.y * 128;
    if (mbase >= ne) return;
    const int n0 = blockIdx.x * 128;

    __shared__ __align__(16) short As[128][40];
    __shared__ __align__(16) short Bs[128][40];

    const int t  = threadIdx.x;
    const int r  = t >> 1;
    const int hf = t & 1;

    int sl = mbase + r; if (sl > ne - 1) sl = ne - 1;
    const unsigned short* arow = pbuf + (size_t)(off0 + sl) * IDIM + hf * 16;
    const float* brow = w2 + (size_t)e * DDIM * IDIM + (size_t)(n0 + r) * IDIM + hf * 16;

    const int lane = t & 63;
    const int wid  = t >> 6;
    const int wm   = wid >> 1;
    const int wn   = wid & 1;
    const int quad = lane >> 4;
    const int l16  = lane & 15;

    floatx4 acc[4][4];
    #pragma unroll
    for (int i = 0; i < 4; i++)
        #pragma unroll
        for (int j = 0; j < 4; j++) acc[i][j] = floatx4{0.f, 0.f, 0.f, 0.f};

    for (int k0 = 0; k0 < IDIM; k0 += 32) {
        // A already bf16: raw 16B copies
        uint4 pa0 = *(const uint4*)(arow + k0 + 0);
        uint4 pa1 = *(const uint4*)(arow + k0 + 8);
        float4 b0 = *(const float4*)(brow + k0 + 0);
        float4 b1 = *(const float4*)(brow + k0 + 4);
        float4 b2 = *(const float4*)(brow + k0 + 8);
        float4 b3 = *(const float4*)(brow + k0 + 12);
        *(uint4*)&As[r][hf * 16 + 0] = pa0;
        *(uint4*)&As[r][hf * 16 + 8] = pa1;
        *(short8*)&Bs[r][hf * 16 + 0] = pack8(b0, b1);
        *(short8*)&Bs[r][hf * 16 + 8] = pack8(b2, b3);
        __syncthreads();

        short8 af[4], bf[4];
        #pragma unroll
        for (int mi = 0; mi < 4; mi++)
            af[mi] = *(short8*)&As[wm * 64 + mi * 16 + l16][quad * 8];
        #pragma unroll
        for (int ni = 0; ni < 4; ni++)
            bf[ni] = *(short8*)&Bs[wn * 64 + ni * 16 + l16][quad * 8];
        #pragma unroll
        for (int mi = 0; mi < 4; mi++)
            #pragma unroll
            for (int ni = 0; ni < 4; ni++)
                acc[mi][ni] = __builtin_amdgcn_mfma_f32_16x16x32_bf16(af[mi], bf[ni], acc[mi][ni], 0, 0, 0);
        __syncthreads();
    }

    // epilogue: scatter fp32 rows to out[pair, :]
    #pragma unroll
    for (int mi = 0; mi < 4; mi++) {
        #pragma unroll
        for (int rr = 0; rr < 4; rr++) {
            const int s2 = mbase + wm * 64 + mi * 16 + quad * 4 + rr;
            if (s2 < ne) {
                const int qq = slot_q[off0 + s2];
                float* orow = out + (size_t)qq * DDIM;
                #pragma unroll
                for (int ni = 0; ni < 4; ni++) {
                    const int col = n0 + wn * 64 + ni * 16 + l16;
                    orow[col] = acc[mi][ni][rr];
                }
            }
        }
    }
}

// ============================================================================
extern "C" void kernel_launch(void* const* d_in, const int* in_sizes, int n_in,
                              void* d_out, int out_size, void* d_ws, size_t ws_size,
                              hipStream_t stream) {
    const float* x    = (const float*)d_in[0];   // (M, D) fp32
    const float* w13  = (const float*)d_in[1];   // (E, 2I, D) fp32
    const float* w2   = (const float*)d_in[2];   // (E, D, I) fp32
    const int*   eidx = (const int*)d_in[3];     // (M, TOPK) int32
    float* out = (float*)d_out;                  // (M, TOPK, D) fp32

    // ws layout: [0,64): offs (E+1 ints); [64, 64+16KB): slot_q; [32768, +16MB): pbuf
    int* offs   = (int*)d_ws;
    int* slot_q = (int*)((char*)d_ws + 64);
    unsigned short* pbuf = (unsigned short*)((char*)d_ws + 32768);

    hipLaunchKernelGGL(route_kernel, dim3(1), dim3(256), 0, stream, eidx, offs, slot_q);
    hipLaunchKernelGGL(gemm1_swiglu, dim3(IDIM / 64, NPAIR / 128, NEXP), dim3(256), 0, stream,
                       x, w13, offs, slot_q, pbuf);
    hipLaunchKernelGGL(gemm2_scatter, dim3(DDIM / 128, NPAIR / 128, NEXP), dim3(256), 0, stream,
                       pbuf, w2, offs, slot_q, out);
}

// Round 2
// 433.420 us; speedup vs baseline: 1.0647x; 1.0647x over previous
//
#include <hip/hip_runtime.h>
#include <hip/hip_bf16.h>
#include <cstdint>
#include <cstddef>

// Problem constants: M=2048, D=1024, I=2048, E=8, TOPK=2
#define DDIM  1024
#define IDIM  2048
#define NEXP  8
#define NPAIR 4096   // M * TOPK
#define KSPLIT 4     // gemm2 K-split factor (occupancy: 256 -> 1024 working blocks)

typedef __attribute__((ext_vector_type(8))) short short8;   // 8 x bf16 (4 VGPRs)
typedef __attribute__((ext_vector_type(4))) float floatx4;  // MFMA accumulator

__device__ inline short8 pack8(float4 a, float4 b) {
    union { short8 s8; __hip_bfloat162 h[4]; } u;
    u.h[0] = __float22bfloat162_rn(float2{a.x, a.y});
    u.h[1] = __float22bfloat162_rn(float2{a.z, a.w});
    u.h[2] = __float22bfloat162_rn(float2{b.x, b.y});
    u.h[3] = __float22bfloat162_rn(float2{b.z, b.w});
    return u.s8;
}

// ============================================================================
// Kernel 1: routing (one block, 1024 thr). offs[e]..offs[e+1] = slot range of
// expert e; slot_q[slot] = pair id q (token = q>>1 since TOPK=2).
// ============================================================================
__global__ void route_kernel(const int* __restrict__ eidx,
                             int* __restrict__ offs,
                             int* __restrict__ slot_q) {
    __shared__ int cnt[NEXP];
    __shared__ int cur[NEXP];
    const int t = threadIdx.x;
    if (t < NEXP) cnt[t] = 0;
    __syncthreads();
    for (int q = t; q < NPAIR; q += 1024) atomicAdd(&cnt[eidx[q]], 1);
    __syncthreads();
    if (t == 0) {
        int s = 0;
        for (int e = 0; e < NEXP; e++) { offs[e] = s; cur[e] = s; s += cnt[e]; }
        offs[NEXP] = s;
    }
    __syncthreads();
    for (int q = t; q < NPAIR; q += 1024) {
        int e = eidx[q];
        int pos = atomicAdd(&cur[e], 1);
        slot_q[pos] = q;
    }
}

// ============================================================================
// Kernel 2: grouped GEMM1 + fused SwiGLU, software-pipelined, dbuf LDS.
//   Tile: 128(M) x 64(N per half), BK=32, 32 K-iters. 4 waves (2x2).
// ============================================================================
__launch_bounds__(256)
__global__ void gemm1_swiglu(const float* __restrict__ x,
                             const float* __restrict__ w13,
                             const int* __restrict__ offs,
                             const int* __restrict__ slot_q,
                             unsigned short* __restrict__ pbuf) {
    const int e    = blockIdx.z;
    const int off0 = offs[e];
    const int ne   = offs[e + 1] - off0;
    const int mbase = blockIdx.y * 128;
    if (mbase >= ne) return;
    const int n0 = blockIdx.x * 64;

    __shared__ __align__(16) short As[2][128][40];
    __shared__ __align__(16) short Bs[2][128][40];   // rows 0..63: w1, 64..127: w3

    const int t  = threadIdx.x;
    const int r  = t >> 1;
    const int hf = t & 1;

    int sl = mbase + r; if (sl > ne - 1) sl = ne - 1;
    const int q = slot_q[off0 + sl];
    const float* __restrict__ arow = x + (size_t)(q >> 1) * DDIM + hf * 16;
    const int wrow = (r < 64) ? (n0 + r) : (IDIM + n0 + (r - 64));
    const float* __restrict__ brow = w13 + (size_t)e * (2 * IDIM) * DDIM + (size_t)wrow * DDIM + hf * 16;

    const int lane = t & 63;
    const int wid  = t >> 6;
    const int wm   = wid >> 1;
    const int wn   = wid & 1;
    const int quad = lane >> 4;
    const int l16  = lane & 15;

    floatx4 acc1[4][2], acc3[4][2];
    #pragma unroll
    for (int i = 0; i < 4; i++)
        #pragma unroll
        for (int j = 0; j < 2; j++) {
            acc1[i][j] = floatx4{0.f, 0.f, 0.f, 0.f};
            acc3[i][j] = floatx4{0.f, 0.f, 0.f, 0.f};
        }

    // ---- prologue: stage iter 0 into buf 0 ----
    {
        float4 a0 = *(const float4*)(arow + 0);
        float4 a1 = *(const float4*)(arow + 4);
        float4 a2 = *(const float4*)(arow + 8);
        float4 a3 = *(const float4*)(arow + 12);
        float4 b0 = *(const float4*)(brow + 0);
        float4 b1 = *(const float4*)(brow + 4);
        float4 b2 = *(const float4*)(brow + 8);
        float4 b3 = *(const float4*)(brow + 12);
        *(short8*)&As[0][r][hf * 16 + 0] = pack8(a0, a1);
        *(short8*)&As[0][r][hf * 16 + 8] = pack8(a2, a3);
        *(short8*)&Bs[0][r][hf * 16 + 0] = pack8(b0, b1);
        *(short8*)&Bs[0][r][hf * 16 + 8] = pack8(b2, b3);
    }
    __syncthreads();

    #pragma unroll 2
    for (int it = 0; it < 32; ++it) {
        const int buf = it & 1;
        // ---- issue next iter's global loads (latency covered by MFMA phase) ----
        float4 a0n, a1n, a2n, a3n, b0n, b1n, b2n, b3n;
        if (it < 31) {
            const float* ap = arow + (it + 1) * 32;
            const float* bp = brow + (it + 1) * 32;
            a0n = *(const float4*)(ap + 0);  a1n = *(const float4*)(ap + 4);
            a2n = *(const float4*)(ap + 8);  a3n = *(const float4*)(ap + 12);
            b0n = *(const float4*)(bp + 0);  b1n = *(const float4*)(bp + 4);
            b2n = *(const float4*)(bp + 8);  b3n = *(const float4*)(bp + 12);
        }
        // ---- compute current buffer ----
        short8 af[4], b1f[2], b3f[2];
        #pragma unroll
        for (int mi = 0; mi < 4; mi++)
            af[mi] = *(short8*)&As[buf][wm * 64 + mi * 16 + l16][quad * 8];
        #pragma unroll
        for (int ni = 0; ni < 2; ni++) {
            b1f[ni] = *(short8*)&Bs[buf][wn * 32 + ni * 16 + l16][quad * 8];
            b3f[ni] = *(short8*)&Bs[buf][64 + wn * 32 + ni * 16 + l16][quad * 8];
        }
        #pragma unroll
        for (int mi = 0; mi < 4; mi++)
            #pragma unroll
            for (int ni = 0; ni < 2; ni++) {
                acc1[mi][ni] = __builtin_amdgcn_mfma_f32_16x16x32_bf16(af[mi], b1f[ni], acc1[mi][ni], 0, 0, 0);
                acc3[mi][ni] = __builtin_amdgcn_mfma_f32_16x16x32_bf16(af[mi], b3f[ni], acc3[mi][ni], 0, 0, 0);
            }
        // ---- stage next iter into other buffer ----
        if (it < 31) {
            *(short8*)&As[buf ^ 1][r][hf * 16 + 0] = pack8(a0n, a1n);
            *(short8*)&As[buf ^ 1][r][hf * 16 + 8] = pack8(a2n, a3n);
            *(short8*)&Bs[buf ^ 1][r][hf * 16 + 0] = pack8(b0n, b1n);
            *(short8*)&Bs[buf ^ 1][r][hf * 16 + 8] = pack8(b2n, b3n);
        }
        __syncthreads();
    }

    // ---- epilogue: p = silu(h1)*h3 -> bf16 ----
    #pragma unroll
    for (int mi = 0; mi < 4; mi++) {
        #pragma unroll
        for (int ni = 0; ni < 2; ni++) {
            const int col = n0 + wn * 32 + ni * 16 + l16;
            #pragma unroll
            for (int rr = 0; rr < 4; rr++) {
                const int s2 = mbase + wm * 64 + mi * 16 + quad * 4 + rr;
                if (s2 < ne) {
                    float v1 = acc1[mi][ni][rr];
                    float v3 = acc3[mi][ni][rr];
                    float pv = v1 / (1.f + __expf(-v1)) * v3;
                    __hip_bfloat16 pb = __float2bfloat16(pv);
                    pbuf[(size_t)(off0 + s2) * IDIM + col] = *(unsigned short*)&pb;
                }
            }
        }
    }
}

// ============================================================================
// Kernel 3: grouped GEMM2 + scatter, K-split x4, pipelined, dbuf LDS.
//   out[q, d] += sum_{i in slice} p[slot, i] * w2[e, d, i]
//   Tile: 128(M) x 128(N), BK=32, 16 K-iters per block. Atomic accumulate.
// ============================================================================
__launch_bounds__(256)
__global__ void gemm2_scatter(const unsigned short* __restrict__ pbuf,
                              const float* __restrict__ w2,
                              const int* __restrict__ offs,
                              const int* __restrict__ slot_q,
                              float* __restrict__ out) {
    const int ez   = blockIdx.z;
    const int e    = ez / KSPLIT;
    const int ks   = ez % KSPLIT;
    const int off0 = offs[e];
    const int ne   = offs[e + 1] - off0;
    const int mbase = blockIdx.y * 128;
    if (mbase >= ne) return;
    const int n0 = blockIdx.x * 128;
    const int kbase = ks * (IDIM / KSPLIT);   // 512

    __shared__ __align__(16) short As[2][128][40];
    __shared__ __align__(16) short Bs[2][128][40];

    const int t  = threadIdx.x;
    const int r  = t >> 1;
    const int hf = t & 1;

    int sl = mbase + r; if (sl > ne - 1) sl = ne - 1;
    const unsigned short* __restrict__ arow = pbuf + (size_t)(off0 + sl) * IDIM + kbase + hf * 16;
    const float* __restrict__ brow = w2 + (size_t)e * DDIM * IDIM + (size_t)(n0 + r) * IDIM + kbase + hf * 16;

    const int lane = t & 63;
    const int wid  = t >> 6;
    const int wm   = wid >> 1;
    const int wn   = wid & 1;
    const int quad = lane >> 4;
    const int l16  = lane & 15;

    floatx4 acc[4][4];
    #pragma unroll
    for (int i = 0; i < 4; i++)
        #pragma unroll
        for (int j = 0; j < 4; j++) acc[i][j] = floatx4{0.f, 0.f, 0.f, 0.f};

    // ---- prologue ----
    {
        uint4 pa0 = *(const uint4*)(arow + 0);
        uint4 pa1 = *(const uint4*)(arow + 8);
        float4 b0 = *(const float4*)(brow + 0);
        float4 b1 = *(const float4*)(brow + 4);
        float4 b2 = *(const float4*)(brow + 8);
        float4 b3 = *(const float4*)(brow + 12);
        *(uint4*)&As[0][r][hf * 16 + 0] = pa0;
        *(uint4*)&As[0][r][hf * 16 + 8] = pa1;
        *(short8*)&Bs[0][r][hf * 16 + 0] = pack8(b0, b1);
        *(short8*)&Bs[0][r][hf * 16 + 8] = pack8(b2, b3);
    }
    __syncthreads();

    const int NK = (IDIM / KSPLIT) / 32;   // 16
    #pragma unroll 2
    for (int it = 0; it < NK; ++it) {
        const int buf = it & 1;
        uint4 pa0n, pa1n; float4 b0n, b1n, b2n, b3n;
        if (it < NK - 1) {
            const unsigned short* ap = arow + (it + 1) * 32;
            const float* bp = brow + (it + 1) * 32;
            pa0n = *(const uint4*)(ap + 0);
            pa1n = *(const uint4*)(ap + 8);
            b0n = *(const float4*)(bp + 0);  b1n = *(const float4*)(bp + 4);
            b2n = *(const float4*)(bp + 8);  b3n = *(const float4*)(bp + 12);
        }
        short8 af[4], bf[4];
        #pragma unroll
        for (int mi = 0; mi < 4; mi++)
            af[mi] = *(short8*)&As[buf][wm * 64 + mi * 16 + l16][quad * 8];
        #pragma unroll
        for (int ni = 0; ni < 4; ni++)
            bf[ni] = *(short8*)&Bs[buf][wn * 64 + ni * 16 + l16][quad * 8];
        #pragma unroll
        for (int mi = 0; mi < 4; mi++)
            #pragma unroll
            for (int ni = 0; ni < 4; ni++)
                acc[mi][ni] = __builtin_amdgcn_mfma_f32_16x16x32_bf16(af[mi], bf[ni], acc[mi][ni], 0, 0, 0);
        if (it < NK - 1) {
            *(uint4*)&As[buf ^ 1][r][hf * 16 + 0] = pa0n;
            *(uint4*)&As[buf ^ 1][r][hf * 16 + 8] = pa1n;
            *(short8*)&Bs[buf ^ 1][r][hf * 16 + 0] = pack8(b0n, b1n);
            *(short8*)&Bs[buf ^ 1][r][hf * 16 + 8] = pack8(b2n, b3n);
        }
        __syncthreads();
    }

    // ---- epilogue: atomic scatter-accumulate into out (zeroed by memset) ----
    #pragma unroll
    for (int mi = 0; mi < 4; mi++) {
        #pragma unroll
        for (int rr = 0; rr < 4; rr++) {
            const int s2 = mbase + wm * 64 + mi * 16 + quad * 4 + rr;
            if (s2 < ne) {
                const int qq = slot_q[off0 + s2];
                float* orow = out + (size_t)qq * DDIM;
                #pragma unroll
                for (int ni = 0; ni < 4; ni++) {
                    const int col = n0 + wn * 64 + ni * 16 + l16;
                    unsafeAtomicAdd(&orow[col], acc[mi][ni][rr]);
                }
            }
        }
    }
}

// ============================================================================
extern "C" void kernel_launch(void* const* d_in, const int* in_sizes, int n_in,
                              void* d_out, int out_size, void* d_ws, size_t ws_size,
                              hipStream_t stream) {
    const float* x    = (const float*)d_in[0];   // (M, D) fp32
    const float* w13  = (const float*)d_in[1];   // (E, 2I, D) fp32
    const float* w2   = (const float*)d_in[2];   // (E, D, I) fp32
    const int*   eidx = (const int*)d_in[3];     // (M, TOPK) int32
    float* out = (float*)d_out;                  // (M, TOPK, D) fp32

    int* offs   = (int*)d_ws;
    int* slot_q = (int*)((char*)d_ws + 64);
    unsigned short* pbuf = (unsigned short*)((char*)d_ws + 32768);

    hipMemsetAsync(d_out, 0, (size_t)out_size * sizeof(float), stream);
    hipLaunchKernelGGL(route_kernel, dim3(1), dim3(1024), 0, stream, eidx, offs, slot_q);
    hipLaunchKernelGGL(gemm1_swiglu, dim3(IDIM / 64, NPAIR / 128, NEXP), dim3(256), 0, stream,
                       x, w13, offs, slot_q, pbuf);
    hipLaunchKernelGGL(gemm2_scatter, dim3(DDIM / 128, NPAIR / 128, NEXP * KSPLIT), dim3(256), 0, stream,
                       pbuf, w2, offs, slot_q, out);
}

// Round 3
// 409.183 us; speedup vs baseline: 1.1278x; 1.0592x over previous
//
#include <hip/hip_runtime.h>
#include <hip/hip_bf16.h>
#include <cstdint>
#include <cstddef>

// Problem constants: M=2048, D=1024, I=2048, E=8, TOPK=2
#define DDIM  1024
#define IDIM  2048
#define NEXP  8
#define NPAIR 4096
#define KSPLIT 4

typedef __attribute__((ext_vector_type(8))) short short8;
typedef __attribute__((ext_vector_type(4))) float floatx4;

__device__ inline short8 pack8(float4 a, float4 b) {
    union { short8 s8; __hip_bfloat162 h[4]; } u;
    u.h[0] = __float22bfloat162_rn(float2{a.x, a.y});
    u.h[1] = __float22bfloat162_rn(float2{a.z, a.w});
    u.h[2] = __float22bfloat162_rn(float2{b.x, b.y});
    u.h[3] = __float22bfloat162_rn(float2{b.z, b.w});
    return u.s8;
}

__device__ inline void gload_lds16(const unsigned short* g, unsigned short* l) {
    __builtin_amdgcn_global_load_lds((const __attribute__((address_space(1))) void*)g,
                                     (__attribute__((address_space(3))) void*)l, 16, 0, 0);
}

// ============================================================================
// fp32 -> bf16 bulk convert (8 elems/thread)
// ============================================================================
__global__ void cvt_bf16(const float4* __restrict__ in, uint4* __restrict__ outp) {
    const int i = blockIdx.x * blockDim.x + threadIdx.x;
    float4 a = in[2 * i], b = in[2 * i + 1];
    short8 p = pack8(a, b);
    outp[i] = *(uint4*)&p;
}

// ============================================================================
// routing: offs[e]..offs[e+1] = slot range; slot_q[slot] = pair id q (tok=q>>1)
// ============================================================================
__global__ void route_kernel(const int* __restrict__ eidx,
                             int* __restrict__ offs,
                             int* __restrict__ slot_q) {
    __shared__ int cnt[NEXP];
    __shared__ int cur[NEXP];
    const int t = threadIdx.x;
    if (t < NEXP) cnt[t] = 0;
    __syncthreads();
    for (int q = t; q < NPAIR; q += 1024) atomicAdd(&cnt[eidx[q]], 1);
    __syncthreads();
    if (t == 0) {
        int s = 0;
        for (int e = 0; e < NEXP; e++) { offs[e] = s; cur[e] = s; s += cnt[e]; }
        offs[NEXP] = s;
    }
    __syncthreads();
    for (int q = t; q < NPAIR; q += 1024) {
        int e = eidx[q];
        int pos = atomicAdd(&cur[e], 1);
        slot_q[pos] = q;
    }
}

// ============================================================================
// GEMM1 + SwiGLU, m97-style: BK=32, 16KB LDS, global_load_lds staging.
// LDS tile layout: 128 rows x 32 bf16 (64B rows = 4 chunks of 16B), chunk
// (r, s) stores global sub-chunk s ^ (r&3)  [XOR swizzle -> 4-way ds conflicts]
// ============================================================================
__launch_bounds__(256)
__global__ void gemm1_swiglu(const unsigned short* __restrict__ xb,
                             const unsigned short* __restrict__ w13b,
                             const int* __restrict__ offs,
                             const int* __restrict__ slot_q,
                             unsigned short* __restrict__ pbuf) {
    const int e    = blockIdx.z;
    const int off0 = offs[e];
    const int ne   = offs[e + 1] - off0;
    const int mbase = blockIdx.y * 128;
    if (mbase >= ne) return;
    const int n0 = blockIdx.x * 64;

    __shared__ __align__(16) unsigned short As[128 * 32];
    __shared__ __align__(16) unsigned short Bs[128 * 32];

    const int t    = threadIdx.x;
    const int lane = t & 63;
    const int wid  = t >> 6;

    // staging: thread t stages chunk c*256+t (c=0,1); row r = idx>>2
    const int r0 = t >> 2;                 // c=0 row (0..63); c=1 row = r0+64
    const int sg = (t & 3) ^ (r0 & 3);     // swizzled source sub-chunk
    int slA0 = mbase + r0;      if (slA0 > ne - 1) slA0 = ne - 1;
    int slA1 = mbase + r0 + 64; if (slA1 > ne - 1) slA1 = ne - 1;
    const unsigned short* pA0 = xb + (size_t)(slot_q[off0 + slA0] >> 1) * DDIM + sg * 8;
    const unsigned short* pA1 = xb + (size_t)(slot_q[off0 + slA1] >> 1) * DDIM + sg * 8;
    const unsigned short* wbase = w13b + (size_t)e * (2 * IDIM) * DDIM;
    const unsigned short* pB0 = wbase + (size_t)(n0 + r0) * DDIM + sg * 8;          // w1
    const unsigned short* pB1 = wbase + (size_t)(IDIM + n0 + r0) * DDIM + sg * 8;   // w3
    // wave-uniform LDS bases (shorts): chunk idx = c*256 + wid*64 + lane
    unsigned short* lA0 = As + wid * 512;
    unsigned short* lA1 = As + 2048 + wid * 512;
    unsigned short* lB0 = Bs + wid * 512;
    unsigned short* lB1 = Bs + 2048 + wid * 512;

    const int wm = wid >> 1, wn = wid & 1;
    const int quad = lane >> 4, l16 = lane & 15;
    const int swz = (quad ^ (l16 & 3)) * 8;   // fragment col offset (shorts)

    floatx4 acc1[4][2], acc3[4][2];
    #pragma unroll
    for (int i = 0; i < 4; i++)
        #pragma unroll
        for (int j = 0; j < 2; j++) {
            acc1[i][j] = floatx4{0.f, 0.f, 0.f, 0.f};
            acc3[i][j] = floatx4{0.f, 0.f, 0.f, 0.f};
        }

    for (int it = 0; it < DDIM / 32; ++it) {
        const int ko = it * 32;
        __syncthreads();
        gload_lds16(pA0 + ko, lA0);
        gload_lds16(pA1 + ko, lA1);
        gload_lds16(pB0 + ko, lB0);
        gload_lds16(pB1 + ko, lB1);
        __syncthreads();

        short8 af[4], b1f[2], b3f[2];
        #pragma unroll
        for (int mi = 0; mi < 4; mi++)
            af[mi] = *(short8*)&As[(wm * 64 + mi * 16 + l16) * 32 + swz];
        #pragma unroll
        for (int ni = 0; ni < 2; ni++) {
            b1f[ni] = *(short8*)&Bs[(wn * 32 + ni * 16 + l16) * 32 + swz];
            b3f[ni] = *(short8*)&Bs[(64 + wn * 32 + ni * 16 + l16) * 32 + swz];
        }
        #pragma unroll
        for (int mi = 0; mi < 4; mi++)
            #pragma unroll
            for (int ni = 0; ni < 2; ni++) {
                acc1[mi][ni] = __builtin_amdgcn_mfma_f32_16x16x32_bf16(af[mi], b1f[ni], acc1[mi][ni], 0, 0, 0);
                acc3[mi][ni] = __builtin_amdgcn_mfma_f32_16x16x32_bf16(af[mi], b3f[ni], acc3[mi][ni], 0, 0, 0);
            }
    }

    #pragma unroll
    for (int mi = 0; mi < 4; mi++) {
        #pragma unroll
        for (int ni = 0; ni < 2; ni++) {
            const int col = n0 + wn * 32 + ni * 16 + l16;
            #pragma unroll
            for (int rr = 0; rr < 4; rr++) {
                const int s2 = mbase + wm * 64 + mi * 16 + quad * 4 + rr;
                if (s2 < ne) {
                    float v1 = acc1[mi][ni][rr];
                    float v3 = acc3[mi][ni][rr];
                    float pv = v1 / (1.f + __expf(-v1)) * v3;
                    __hip_bfloat16 pb = __float2bfloat16(pv);
                    pbuf[(size_t)(off0 + s2) * IDIM + col] = *(unsigned short*)&pb;
                }
            }
        }
    }
}

// ============================================================================
// GEMM2 + scatter, m97-style, K-split x4, atomic accumulate into zeroed out.
// ============================================================================
__launch_bounds__(256)
__global__ void gemm2_scatter(const unsigned short* __restrict__ pbuf,
                              const unsigned short* __restrict__ w2b,
                              const int* __restrict__ offs,
                              const int* __restrict__ slot_q,
                              float* __restrict__ out) {
    const int ez   = blockIdx.z;
    const int e    = ez >> 2;
    const int ks   = ez & 3;
    const int off0 = offs[e];
    const int ne   = offs[e + 1] - off0;
    const int mbase = blockIdx.y * 128;
    if (mbase >= ne) return;
    const int n0 = blockIdx.x * 128;
    const int kbase = ks * (IDIM / KSPLIT);

    __shared__ __align__(16) unsigned short As[128 * 32];
    __shared__ __align__(16) unsigned short Bs[128 * 32];

    const int t    = threadIdx.x;
    const int lane = t & 63;
    const int wid  = t >> 6;

    const int r0 = t >> 2;
    const int sg = (t & 3) ^ (r0 & 3);
    int slA0 = mbase + r0;      if (slA0 > ne - 1) slA0 = ne - 1;
    int slA1 = mbase + r0 + 64; if (slA1 > ne - 1) slA1 = ne - 1;
    const unsigned short* pA0 = pbuf + (size_t)(off0 + slA0) * IDIM + kbase + sg * 8;
    const unsigned short* pA1 = pbuf + (size_t)(off0 + slA1) * IDIM + kbase + sg * 8;
    const unsigned short* wbase = w2b + (size_t)e * DDIM * IDIM;
    const unsigned short* pB0 = wbase + (size_t)(n0 + r0) * IDIM + kbase + sg * 8;
    const unsigned short* pB1 = wbase + (size_t)(n0 + 64 + r0) * IDIM + kbase + sg * 8;
    unsigned short* lA0 = As + wid * 512;
    unsigned short* lA1 = As + 2048 + wid * 512;
    unsigned short* lB0 = Bs + wid * 512;
    unsigned short* lB1 = Bs + 2048 + wid * 512;

    const int wm = wid >> 1, wn = wid & 1;
    const int quad = lane >> 4, l16 = lane & 15;
    const int swz = (quad ^ (l16 & 3)) * 8;

    floatx4 acc[4][4];
    #pragma unroll
    for (int i = 0; i < 4; i++)
        #pragma unroll
        for (int j = 0; j < 4; j++) acc[i][j] = floatx4{0.f, 0.f, 0.f, 0.f};

    for (int it = 0; it < (IDIM / KSPLIT) / 32; ++it) {
        const int ko = it * 32;
        __syncthreads();
        gload_lds16(pA0 + ko, lA0);
        gload_lds16(pA1 + ko, lA1);
        gload_lds16(pB0 + ko, lB0);
        gload_lds16(pB1 + ko, lB1);
        __syncthreads();

        short8 af[4], bf[4];
        #pragma unroll
        for (int mi = 0; mi < 4; mi++)
            af[mi] = *(short8*)&As[(wm * 64 + mi * 16 + l16) * 32 + swz];
        #pragma unroll
        for (int ni = 0; ni < 4; ni++)
            bf[ni] = *(short8*)&Bs[(wn * 64 + ni * 16 + l16) * 32 + swz];
        #pragma unroll
        for (int mi = 0; mi < 4; mi++)
            #pragma unroll
            for (int ni = 0; ni < 4; ni++)
                acc[mi][ni] = __builtin_amdgcn_mfma_f32_16x16x32_bf16(af[mi], bf[ni], acc[mi][ni], 0, 0, 0);
    }

    #pragma unroll
    for (int mi = 0; mi < 4; mi++) {
        #pragma unroll
        for (int rr = 0; rr < 4; rr++) {
            const int s2 = mbase + wm * 64 + mi * 16 + quad * 4 + rr;
            if (s2 < ne) {
                const int qq = slot_q[off0 + s2];
                float* orow = out + (size_t)qq * DDIM;
                #pragma unroll
                for (int ni = 0; ni < 4; ni++)
                    unsafeAtomicAdd(&orow[n0 + wn * 64 + ni * 16 + l16], acc[mi][ni][rr]);
            }
        }
    }
}

// ============================================================================
// Fallback path (R2 kernels, fp32 sources) if ws is too small for bf16 copies.
// ============================================================================
__launch_bounds__(256)
__global__ void gemm1_fb(const float* __restrict__ x, const float* __restrict__ w13,
                         const int* __restrict__ offs, const int* __restrict__ slot_q,
                         unsigned short* __restrict__ pbuf) {
    const int e = blockIdx.z, off0 = offs[e], ne = offs[e + 1] - off0;
    const int mbase = blockIdx.y * 128;
    if (mbase >= ne) return;
    const int n0 = blockIdx.x * 64;
    __shared__ __align__(16) short As[128][40];
    __shared__ __align__(16) short Bs[128][40];
    const int t = threadIdx.x, r = t >> 1, hf = t & 1;
    int sl = mbase + r; if (sl > ne - 1) sl = ne - 1;
    const int q = slot_q[off0 + sl];
    const float* arow = x + (size_t)(q >> 1) * DDIM + hf * 16;
    const int wrow = (r < 64) ? (n0 + r) : (IDIM + n0 + (r - 64));
    const float* brow = w13 + (size_t)e * (2 * IDIM) * DDIM + (size_t)wrow * DDIM + hf * 16;
    const int lane = t & 63, wid = t >> 6, wm = wid >> 1, wn = wid & 1;
    const int quad = lane >> 4, l16 = lane & 15;
    floatx4 acc1[4][2], acc3[4][2];
    #pragma unroll
    for (int i = 0; i < 4; i++)
        #pragma unroll
        for (int j = 0; j < 2; j++) { acc1[i][j] = floatx4{0,0,0,0}; acc3[i][j] = floatx4{0,0,0,0}; }
    for (int k0 = 0; k0 < DDIM; k0 += 32) {
        float4 a0 = *(const float4*)(arow + k0), a1 = *(const float4*)(arow + k0 + 4);
        float4 a2 = *(const float4*)(arow + k0 + 8), a3 = *(const float4*)(arow + k0 + 12);
        float4 b0 = *(const float4*)(brow + k0), b1 = *(const float4*)(brow + k0 + 4);
        float4 b2 = *(const float4*)(brow + k0 + 8), b3 = *(const float4*)(brow + k0 + 12);
        *(short8*)&As[r][hf * 16] = pack8(a0, a1); *(short8*)&As[r][hf * 16 + 8] = pack8(a2, a3);
        *(short8*)&Bs[r][hf * 16] = pack8(b0, b1); *(short8*)&Bs[r][hf * 16 + 8] = pack8(b2, b3);
        __syncthreads();
        short8 af[4], b1f[2], b3f[2];
        #pragma unroll
        for (int mi = 0; mi < 4; mi++) af[mi] = *(short8*)&As[wm * 64 + mi * 16 + l16][quad * 8];
        #pragma unroll
        for (int ni = 0; ni < 2; ni++) {
            b1f[ni] = *(short8*)&Bs[wn * 32 + ni * 16 + l16][quad * 8];
            b3f[ni] = *(short8*)&Bs[64 + wn * 32 + ni * 16 + l16][quad * 8];
        }
        #pragma unroll
        for (int mi = 0; mi < 4; mi++)
            #pragma unroll
            for (int ni = 0; ni < 2; ni++) {
                acc1[mi][ni] = __builtin_amdgcn_mfma_f32_16x16x32_bf16(af[mi], b1f[ni], acc1[mi][ni], 0, 0, 0);
                acc3[mi][ni] = __builtin_amdgcn_mfma_f32_16x16x32_bf16(af[mi], b3f[ni], acc3[mi][ni], 0, 0, 0);
            }
        __syncthreads();
    }
    #pragma unroll
    for (int mi = 0; mi < 4; mi++)
        #pragma unroll
        for (int ni = 0; ni < 2; ni++) {
            const int col = n0 + wn * 32 + ni * 16 + l16;
            #pragma unroll
            for (int rr = 0; rr < 4; rr++) {
                const int s2 = mbase + wm * 64 + mi * 16 + quad * 4 + rr;
                if (s2 < ne) {
                    float v1 = acc1[mi][ni][rr], v3 = acc3[mi][ni][rr];
                    float pv = v1 / (1.f + __expf(-v1)) * v3;
                    __hip_bfloat16 pb = __float2bfloat16(pv);
                    pbuf[(size_t)(off0 + s2) * IDIM + col] = *(unsigned short*)&pb;
                }
            }
        }
}

__launch_bounds__(256)
__global__ void gemm2_fb(const unsigned short* __restrict__ pbuf, const float* __restrict__ w2,
                         const int* __restrict__ offs, const int* __restrict__ slot_q,
                         float* __restrict__ out) {
    const int ez = blockIdx.z, e = ez >> 2, ks = ez & 3;
    const int off0 = offs[e], ne = offs[e + 1] - off0;
    const int mbase = blockIdx.y * 128;
    if (mbase >= ne) return;
    const int n0 = blockIdx.x * 128, kbase = ks * (IDIM / KSPLIT);
    __shared__ __align__(16) short As[128][40];
    __shared__ __align__(16) short Bs[128][40];
    const int t = threadIdx.x, r = t >> 1, hf = t & 1;
    int sl = mbase + r; if (sl > ne - 1) sl = ne - 1;
    const unsigned short* arow = pbuf + (size_t)(off0 + sl) * IDIM + kbase + hf * 16;
    const float* brow = w2 + (size_t)e * DDIM * IDIM + (size_t)(n0 + r) * IDIM + kbase + hf * 16;
    const int lane = t & 63, wid = t >> 6, wm = wid >> 1, wn = wid & 1;
    const int quad = lane >> 4, l16 = lane & 15;
    floatx4 acc[4][4];
    #pragma unroll
    for (int i = 0; i < 4; i++)
        #pragma unroll
        for (int j = 0; j < 4; j++) acc[i][j] = floatx4{0,0,0,0};
    for (int k0 = 0; k0 < IDIM / KSPLIT; k0 += 32) {
        uint4 pa0 = *(const uint4*)(arow + k0), pa1 = *(const uint4*)(arow + k0 + 8);
        float4 b0 = *(const float4*)(brow + k0), b1 = *(const float4*)(brow + k0 + 4);
        float4 b2 = *(const float4*)(brow + k0 + 8), b3 = *(const float4*)(brow + k0 + 12);
        *(uint4*)&As[r][hf * 16] = pa0; *(uint4*)&As[r][hf * 16 + 8] = pa1;
        *(short8*)&Bs[r][hf * 16] = pack8(b0, b1); *(short8*)&Bs[r][hf * 16 + 8] = pack8(b2, b3);
        __syncthreads();
        short8 af[4], bf[4];
        #pragma unroll
        for (int mi = 0; mi < 4; mi++) af[mi] = *(short8*)&As[wm * 64 + mi * 16 + l16][quad * 8];
        #pragma unroll
        for (int ni = 0; ni < 4; ni++) bf[ni] = *(short8*)&Bs[wn * 64 + ni * 16 + l16][quad * 8];
        #pragma unroll
        for (int mi = 0; mi < 4; mi++)
            #pragma unroll
            for (int ni = 0; ni < 4; ni++)
                acc[mi][ni] = __builtin_amdgcn_mfma_f32_16x16x32_bf16(af[mi], bf[ni], acc[mi][ni], 0, 0, 0);
        __syncthreads();
    }
    #pragma unroll
    for (int mi = 0; mi < 4; mi++)
        #pragma unroll
        for (int rr = 0; rr < 4; rr++) {
            const int s2 = mbase + wm * 64 + mi * 16 + quad * 4 + rr;
            if (s2 < ne) {
                const int qq = slot_q[off0 + s2];
                #pragma unroll
                for (int ni = 0; ni < 4; ni++)
                    unsafeAtomicAdd(&out[(size_t)qq * DDIM + n0 + wn * 64 + ni * 16 + l16], acc[mi][ni][rr]);
            }
        }
}

// ============================================================================
extern "C" void kernel_launch(void* const* d_in, const int* in_sizes, int n_in,
                              void* d_out, int out_size, void* d_ws, size_t ws_size,
                              hipStream_t stream) {
    const float* x    = (const float*)d_in[0];
    const float* w13  = (const float*)d_in[1];
    const float* w2   = (const float*)d_in[2];
    const int*   eidx = (const int*)d_in[3];
    float* out = (float*)d_out;

    // main-path ws layout
    const size_t OFF_XB   = 65536;
    const size_t OFF_W13B = OFF_XB + 4194304;          // 4,259,840
    const size_t OFF_W2B  = OFF_W13B + 67108864;       // 71,368,704
    const size_t OFF_PBUF = OFF_W2B + 33554432;        // 104,923,136
    const size_t NEED     = OFF_PBUF + 16777216;       // 121,700,352

    hipMemsetAsync(d_out, 0, (size_t)out_size * sizeof(float), stream);

    if (ws_size >= NEED) {
        int* offs   = (int*)d_ws;
        int* slot_q = (int*)((char*)d_ws + 256);
        unsigned short* xb   = (unsigned short*)((char*)d_ws + OFF_XB);
        unsigned short* w13b = (unsigned short*)((char*)d_ws + OFF_W13B);
        unsigned short* w2b  = (unsigned short*)((char*)d_ws + OFF_W2B);
        unsigned short* pbuf = (unsigned short*)((char*)d_ws + OFF_PBUF);

        hipLaunchKernelGGL(cvt_bf16, dim3(1024),  dim3(256), 0, stream, (const float4*)x,   (uint4*)xb);
        hipLaunchKernelGGL(cvt_bf16, dim3(16384), dim3(256), 0, stream, (const float4*)w13, (uint4*)w13b);
        hipLaunchKernelGGL(cvt_bf16, dim3(8192),  dim3(256), 0, stream, (const float4*)w2,  (uint4*)w2b);
        hipLaunchKernelGGL(route_kernel, dim3(1), dim3(1024), 0, stream, eidx, offs, slot_q);
        hipLaunchKernelGGL(gemm1_swiglu, dim3(IDIM / 64, 32, NEXP), dim3(256), 0, stream,
                           xb, w13b, offs, slot_q, pbuf);
        hipLaunchKernelGGL(gemm2_scatter, dim3(DDIM / 128, 32, NEXP * KSPLIT), dim3(256), 0, stream,
                           pbuf, w2b, offs, slot_q, out);
    } else {
        int* offs   = (int*)d_ws;
        int* slot_q = (int*)((char*)d_ws + 64);
        unsigned short* pbuf = (unsigned short*)((char*)d_ws + 32768);
        hipLaunchKernelGGL(route_kernel, dim3(1), dim3(1024), 0, stream, eidx, offs, slot_q);
        hipLaunchKernelGGL(gemm1_fb, dim3(IDIM / 64, 32, NEXP), dim3(256), 0, stream,
                           x, w13, offs, slot_q, pbuf);
        hipLaunchKernelGGL(gemm2_fb, dim3(DDIM / 128, 32, NEXP * KSPLIT), dim3(256), 0, stream,
                           pbuf, w2, offs, slot_q, out);
    }
}

// Round 4
// 386.178 us; speedup vs baseline: 1.1950x; 1.0596x over previous
//
#include <hip/hip_runtime.h>
#include <hip/hip_bf16.h>
#include <cstdint>
#include <cstddef>

// Problem constants: M=2048, D=1024, I=2048, E=8, TOPK=2
#define DDIM  1024
#define IDIM  2048
#define NEXP  8
#define NPAIR 4096
#define KSPLIT 2
#define MAXTILE 40   // max m-tiles: 32 + 8 rounding

typedef __attribute__((ext_vector_type(8))) short short8;
typedef __attribute__((ext_vector_type(4))) float floatx4;

__device__ inline short8 pack8(float4 a, float4 b) {
    union { short8 s8; __hip_bfloat162 h[4]; } u;
    u.h[0] = __float22bfloat162_rn(float2{a.x, a.y});
    u.h[1] = __float22bfloat162_rn(float2{a.z, a.w});
    u.h[2] = __float22bfloat162_rn(float2{b.x, b.y});
    u.h[3] = __float22bfloat162_rn(float2{b.z, b.w});
    return u.s8;
}

__device__ inline void gload_lds16(const unsigned short* g, unsigned short* l) {
    __builtin_amdgcn_global_load_lds((const __attribute__((address_space(1))) void*)g,
                                     (__attribute__((address_space(3))) void*)l, 16, 0, 0);
}

// ============================================================================
// Single-pass fp32 -> bf16 convert of x, w13, w2 (8 elems / thread)
// ============================================================================
__global__ void cvt_all(const float4* __restrict__ x, const float4* __restrict__ w13,
                        const float4* __restrict__ w2,
                        uint4* __restrict__ xb, uint4* __restrict__ w13b,
                        uint4* __restrict__ w2b) {
    const int i = blockIdx.x * 256 + threadIdx.x;
    const int NX   = (2048 * 1024) / 8;       // 262144
    const int NW13 = (8 * 4096 * 1024) / 8;   // 4194304
    const float4* src; uint4* dst; int j;
    if (i < NX)              { src = x;   dst = xb;   j = i; }
    else if (i < NX + NW13)  { src = w13; dst = w13b; j = i - NX; }
    else                     { src = w2;  dst = w2b;  j = i - NX - NW13; }
    float4 a = src[2 * j], b = src[2 * j + 1];
    short8 p = pack8(a, b);
    dst[j] = *(uint4*)&p;
}

// ============================================================================
// Routing + dense tile table. tbl[i] = {e, mbase, off0, ne}; padded to MAXTILE
// with {0,0,0,0} (guard mbase>=ne catches them). slot_q[slot] = pair id q.
// ============================================================================
__global__ void route_kernel(const int* __restrict__ eidx,
                             int4* __restrict__ tbl,
                             int* __restrict__ slot_q) {
    __shared__ int cnt[NEXP];
    __shared__ int base[NEXP];
    __shared__ int cur[NEXP];
    const int t = threadIdx.x;
    if (t < NEXP) cnt[t] = 0;
    __syncthreads();
    for (int q = t; q < NPAIR; q += 1024) atomicAdd(&cnt[eidx[q]], 1);
    __syncthreads();
    if (t == 0) {
        int s = 0, nt = 0;
        for (int e = 0; e < NEXP; e++) {
            base[e] = s; cur[e] = s;
            for (int mb = 0; mb < cnt[e]; mb += 128)
                tbl[nt++] = int4{e, mb, s, cnt[e]};
            s += cnt[e];
        }
        for (; nt < MAXTILE; nt++) tbl[nt] = int4{0, 0, 0, 0};
    }
    __syncthreads();
    for (int q = t; q < NPAIR; q += 1024) {
        int e = eidx[q];
        int pos = atomicAdd(&cur[e], 1);
        slot_q[pos] = q;
    }
}

// ============================================================================
// GEMM1 + SwiGLU, m97-style: BK=32, 16KB LDS, global_load_lds staging.
// grid: (IDIM/64 n-tiles, MAXTILE m-tiles)
// ============================================================================
__launch_bounds__(256)
__global__ void gemm1_swiglu(const unsigned short* __restrict__ xb,
                             const unsigned short* __restrict__ w13b,
                             const int4* __restrict__ tbl,
                             const int* __restrict__ slot_q,
                             unsigned short* __restrict__ pbuf) {
    const int4 tt = tbl[blockIdx.y];
    const int e = tt.x, mbase = tt.y, off0 = tt.z, ne = tt.w;
    if (mbase >= ne) return;
    const int n0 = blockIdx.x * 64;

    __shared__ __align__(16) unsigned short As[128 * 32];
    __shared__ __align__(16) unsigned short Bs[128 * 32];

    const int t    = threadIdx.x;
    const int lane = t & 63;
    const int wid  = t >> 6;

    const int r0 = t >> 2;                 // staging row (c=0); c=1 row = r0+64
    const int sg = (t & 3) ^ (r0 & 3);     // XOR-swizzled source sub-chunk
    int slA0 = mbase + r0;      if (slA0 > ne - 1) slA0 = ne - 1;
    int slA1 = mbase + r0 + 64; if (slA1 > ne - 1) slA1 = ne - 1;
    const unsigned short* pA0 = xb + (size_t)(slot_q[off0 + slA0] >> 1) * DDIM + sg * 8;
    const unsigned short* pA1 = xb + (size_t)(slot_q[off0 + slA1] >> 1) * DDIM + sg * 8;
    const unsigned short* wbase = w13b + (size_t)e * (2 * IDIM) * DDIM;
    const unsigned short* pB0 = wbase + (size_t)(n0 + r0) * DDIM + sg * 8;          // w1
    const unsigned short* pB1 = wbase + (size_t)(IDIM + n0 + r0) * DDIM + sg * 8;   // w3
    unsigned short* lA0 = As + wid * 512;
    unsigned short* lA1 = As + 2048 + wid * 512;
    unsigned short* lB0 = Bs + wid * 512;
    unsigned short* lB1 = Bs + 2048 + wid * 512;

    const int wm = wid >> 1, wn = wid & 1;
    const int quad = lane >> 4, l16 = lane & 15;
    const int swz = (quad ^ (l16 & 3)) * 8;

    floatx4 acc1[4][2], acc3[4][2];
    #pragma unroll
    for (int i = 0; i < 4; i++)
        #pragma unroll
        for (int j = 0; j < 2; j++) {
            acc1[i][j] = floatx4{0.f, 0.f, 0.f, 0.f};
            acc3[i][j] = floatx4{0.f, 0.f, 0.f, 0.f};
        }

    for (int it = 0; it < DDIM / 32; ++it) {
        const int ko = it * 32;
        __syncthreads();
        gload_lds16(pA0 + ko, lA0);
        gload_lds16(pA1 + ko, lA1);
        gload_lds16(pB0 + ko, lB0);
        gload_lds16(pB1 + ko, lB1);
        __syncthreads();

        short8 af[4], b1f[2], b3f[2];
        #pragma unroll
        for (int mi = 0; mi < 4; mi++)
            af[mi] = *(short8*)&As[(wm * 64 + mi * 16 + l16) * 32 + swz];
        #pragma unroll
        for (int ni = 0; ni < 2; ni++) {
            b1f[ni] = *(short8*)&Bs[(wn * 32 + ni * 16 + l16) * 32 + swz];
            b3f[ni] = *(short8*)&Bs[(64 + wn * 32 + ni * 16 + l16) * 32 + swz];
        }
        #pragma unroll
        for (int mi = 0; mi < 4; mi++)
            #pragma unroll
            for (int ni = 0; ni < 2; ni++) {
                acc1[mi][ni] = __builtin_amdgcn_mfma_f32_16x16x32_bf16(af[mi], b1f[ni], acc1[mi][ni], 0, 0, 0);
                acc3[mi][ni] = __builtin_amdgcn_mfma_f32_16x16x32_bf16(af[mi], b3f[ni], acc3[mi][ni], 0, 0, 0);
            }
    }

    #pragma unroll
    for (int mi = 0; mi < 4; mi++) {
        #pragma unroll
        for (int ni = 0; ni < 2; ni++) {
            const int col = n0 + wn * 32 + ni * 16 + l16;
            #pragma unroll
            for (int rr = 0; rr < 4; rr++) {
                const int s2 = mbase + wm * 64 + mi * 16 + quad * 4 + rr;
                if (s2 < ne) {
                    float v1 = acc1[mi][ni][rr];
                    float v3 = acc3[mi][ni][rr];
                    float pv = v1 / (1.f + __expf(-v1)) * v3;
                    __hip_bfloat16 pb = __float2bfloat16(pv);
                    pbuf[(size_t)(off0 + s2) * IDIM + col] = *(unsigned short*)&pb;
                }
            }
        }
    }
}

// ============================================================================
// GEMM2, K-split x2, NO atomics: ks=0 -> out, ks=1 -> partial p1 (plain stores)
// grid: (DDIM/128 n-tiles, MAXTILE m-tiles, KSPLIT)
// ============================================================================
__launch_bounds__(256)
__global__ void gemm2_scatter(const unsigned short* __restrict__ pbuf,
                              const unsigned short* __restrict__ w2b,
                              const int4* __restrict__ tbl,
                              const int* __restrict__ slot_q,
                              float* __restrict__ out,
                              float* __restrict__ p1) {
    const int4 tt = tbl[blockIdx.y];
    const int e = tt.x, mbase = tt.y, off0 = tt.z, ne = tt.w;
    if (mbase >= ne) return;
    const int n0 = blockIdx.x * 128;
    const int ks = blockIdx.z;
    const int kbase = ks * (IDIM / KSPLIT);   // 0 or 1024

    __shared__ __align__(16) unsigned short As[128 * 32];
    __shared__ __align__(16) unsigned short Bs[128 * 32];

    const int t    = threadIdx.x;
    const int lane = t & 63;
    const int wid  = t >> 6;

    const int r0 = t >> 2;
    const int sg = (t & 3) ^ (r0 & 3);
    int slA0 = mbase + r0;      if (slA0 > ne - 1) slA0 = ne - 1;
    int slA1 = mbase + r0 + 64; if (slA1 > ne - 1) slA1 = ne - 1;
    const unsigned short* pA0 = pbuf + (size_t)(off0 + slA0) * IDIM + kbase + sg * 8;
    const unsigned short* pA1 = pbuf + (size_t)(off0 + slA1) * IDIM + kbase + sg * 8;
    const unsigned short* wbase = w2b + (size_t)e * DDIM * IDIM;
    const unsigned short* pB0 = wbase + (size_t)(n0 + r0) * IDIM + kbase + sg * 8;
    const unsigned short* pB1 = wbase + (size_t)(n0 + 64 + r0) * IDIM + kbase + sg * 8;
    unsigned short* lA0 = As + wid * 512;
    unsigned short* lA1 = As + 2048 + wid * 512;
    unsigned short* lB0 = Bs + wid * 512;
    unsigned short* lB1 = Bs + 2048 + wid * 512;

    const int wm = wid >> 1, wn = wid & 1;
    const int quad = lane >> 4, l16 = lane & 15;
    const int swz = (quad ^ (l16 & 3)) * 8;

    floatx4 acc[4][4];
    #pragma unroll
    for (int i = 0; i < 4; i++)
        #pragma unroll
        for (int j = 0; j < 4; j++) acc[i][j] = floatx4{0.f, 0.f, 0.f, 0.f};

    for (int it = 0; it < (IDIM / KSPLIT) / 32; ++it) {
        const int ko = it * 32;
        __syncthreads();
        gload_lds16(pA0 + ko, lA0);
        gload_lds16(pA1 + ko, lA1);
        gload_lds16(pB0 + ko, lB0);
        gload_lds16(pB1 + ko, lB1);
        __syncthreads();

        short8 af[4], bf[4];
        #pragma unroll
        for (int mi = 0; mi < 4; mi++)
            af[mi] = *(short8*)&As[(wm * 64 + mi * 16 + l16) * 32 + swz];
        #pragma unroll
        for (int ni = 0; ni < 4; ni++)
            bf[ni] = *(short8*)&Bs[(wn * 64 + ni * 16 + l16) * 32 + swz];
        #pragma unroll
        for (int mi = 0; mi < 4; mi++)
            #pragma unroll
            for (int ni = 0; ni < 4; ni++)
                acc[mi][ni] = __builtin_amdgcn_mfma_f32_16x16x32_bf16(af[mi], bf[ni], acc[mi][ni], 0, 0, 0);
    }

    float* dstbase = (ks == 0) ? out : p1;
    #pragma unroll
    for (int mi = 0; mi < 4; mi++) {
        #pragma unroll
        for (int rr = 0; rr < 4; rr++) {
            const int s2 = mbase + wm * 64 + mi * 16 + quad * 4 + rr;
            if (s2 < ne) {
                const int qq = slot_q[off0 + s2];
                float* orow = dstbase + (size_t)qq * DDIM;
                #pragma unroll
                for (int ni = 0; ni < 4; ni++)
                    orow[n0 + wn * 64 + ni * 16 + l16] = acc[mi][ni][rr];
            }
        }
    }
}

// ============================================================================
// out += p1  (48 MB traffic)
// ============================================================================
__global__ void reduce_add(float4* __restrict__ out, const float4* __restrict__ p1) {
    const int i = blockIdx.x * 256 + threadIdx.x;
    float4 a = out[i], b = p1[i];
    out[i] = float4{a.x + b.x, a.y + b.y, a.z + b.z, a.w + b.w};
}

// ============================================================================
extern "C" void kernel_launch(void* const* d_in, const int* in_sizes, int n_in,
                              void* d_out, int out_size, void* d_ws, size_t ws_size,
                              hipStream_t stream) {
    const float* x    = (const float*)d_in[0];
    const float* w13  = (const float*)d_in[1];
    const float* w2   = (const float*)d_in[2];
    const int*   eidx = (const int*)d_in[3];
    float* out = (float*)d_out;

    // ws layout (NEED = 121,700,352 B — R3 confirmed available):
    //   [128, 768): tile table (40 x int4)
    //   [1024, 17408): slot_q
    //   [OFF_XB, +4MB): xb ; [OFF_W13B, +64MB): w13b (dead after gemm1 ->
    //   first 16MB reused as gemm2 partial p1) ; [OFF_W2B, +32MB): w2b ;
    //   [OFF_PBUF, +16MB): pbuf
    const size_t OFF_XB   = 65536;
    const size_t OFF_W13B = OFF_XB + (size_t)4 * 1024 * 1024;
    const size_t OFF_W2B  = OFF_W13B + (size_t)64 * 1024 * 1024;
    const size_t OFF_PBUF = OFF_W2B + (size_t)32 * 1024 * 1024;

    int4* tbl   = (int4*)((char*)d_ws + 128);
    int* slot_q = (int*)((char*)d_ws + 1024);
    unsigned short* xb   = (unsigned short*)((char*)d_ws + OFF_XB);
    unsigned short* w13b = (unsigned short*)((char*)d_ws + OFF_W13B);
    unsigned short* w2b  = (unsigned short*)((char*)d_ws + OFF_W2B);
    unsigned short* pbuf = (unsigned short*)((char*)d_ws + OFF_PBUF);
    float* p1 = (float*)((char*)d_ws + OFF_W13B);   // reuse (16 MB of 64 MB)

    // 262144 + 4194304 + 2097152 = 6,553,600 threads = 25600 blocks
    hipLaunchKernelGGL(cvt_all, dim3(25600), dim3(256), 0, stream,
                       (const float4*)x, (const float4*)w13, (const float4*)w2,
                       (uint4*)xb, (uint4*)w13b, (uint4*)w2b);
    hipLaunchKernelGGL(route_kernel, dim3(1), dim3(1024), 0, stream, eidx, tbl, slot_q);
    hipLaunchKernelGGL(gemm1_swiglu, dim3(IDIM / 64, MAXTILE), dim3(256), 0, stream,
                       xb, w13b, tbl, slot_q, pbuf);
    hipLaunchKernelGGL(gemm2_scatter, dim3(DDIM / 128, MAXTILE, KSPLIT), dim3(256), 0, stream,
                       pbuf, w2b, tbl, slot_q, out, p1);
    hipLaunchKernelGGL(reduce_add, dim3((NPAIR * DDIM / 4) / 256), dim3(256), 0, stream,
                       (float4*)out, (const float4*)p1);
}

// Round 6
// 383.669 us; speedup vs baseline: 1.2028x; 1.0065x over previous
//
#include <hip/hip_runtime.h>
#include <hip/hip_bf16.h>
#include <cstdint>
#include <cstddef>

// Problem constants: M=2048, D=1024, I=2048, E=8, TOPK=2
#define DDIM  1024
#define IDIM  2048
#define NEXP  8
#define NPAIR 4096
#define KSPLIT 4
#define MAXTILE 40   // max m-tiles: 32 + 8 rounding

typedef __attribute__((ext_vector_type(8))) short short8;
typedef __attribute__((ext_vector_type(4))) float floatx4;
typedef __attribute__((ext_vector_type(4))) float fvec4;   // native vec for nontemporal builtins

__device__ inline short8 pack8(float4 a, float4 b) {
    union { short8 s8; __hip_bfloat162 h[4]; } u;
    u.h[0] = __float22bfloat162_rn(float2{a.x, a.y});
    u.h[1] = __float22bfloat162_rn(float2{a.z, a.w});
    u.h[2] = __float22bfloat162_rn(float2{b.x, b.y});
    u.h[3] = __float22bfloat162_rn(float2{b.z, b.w});
    return u.s8;
}

__device__ inline short8 pack8v(fvec4 a, fvec4 b) {
    union { short8 s8; __hip_bfloat162 h[4]; } u;
    u.h[0] = __float22bfloat162_rn(float2{a.x, a.y});
    u.h[1] = __float22bfloat162_rn(float2{a.z, a.w});
    u.h[2] = __float22bfloat162_rn(float2{b.x, b.y});
    u.h[3] = __float22bfloat162_rn(float2{b.z, b.w});
    return u.s8;
}

__device__ inline void gload_lds16(const unsigned short* g, unsigned short* l) {
    __builtin_amdgcn_global_load_lds((const __attribute__((address_space(1))) void*)g,
                                     (__attribute__((address_space(3))) void*)l, 16, 0, 0);
}

// ============================================================================
// fp32 -> bf16 convert of x,w13,w2. Grid-stride, 16 floats/iter/thread,
// nontemporal fp32 loads (read-once; keep L2/L3 for the bf16 outputs).
// ============================================================================
__global__ void cvt_all(const fvec4* __restrict__ x, const fvec4* __restrict__ w13,
                        const fvec4* __restrict__ w2,
                        uint4* __restrict__ xb, uint4* __restrict__ w13b,
                        uint4* __restrict__ w2b) {
    const int NX   = (2048 * 1024) / 8;       // 262144 pairs (8 floats each)
    const int NW13 = (8 * 4096 * 1024) / 8;   // 4194304
    const int NW2  = (8 * 1024 * 2048) / 8;   // 2097152
    const int total2 = (NX + NW13 + NW2) / 2; // process 2 pairs / iter
    for (int i2 = blockIdx.x * 256 + threadIdx.x; i2 < total2; i2 += gridDim.x * 256) {
        const int i = 2 * i2;
        const fvec4* src; uint4* dst; int j;
        if (i < NX)              { src = x;   dst = xb;   j = i; }
        else if (i < NX + NW13)  { src = w13; dst = w13b; j = i - NX; }
        else                     { src = w2;  dst = w2b;  j = i - NX - NW13; }
        fvec4 a0 = __builtin_nontemporal_load(src + 2 * j + 0);
        fvec4 a1 = __builtin_nontemporal_load(src + 2 * j + 1);
        fvec4 a2 = __builtin_nontemporal_load(src + 2 * j + 2);
        fvec4 a3 = __builtin_nontemporal_load(src + 2 * j + 3);
        short8 p0 = pack8v(a0, a1);
        short8 p1 = pack8v(a2, a3);
        dst[j]     = *(uint4*)&p0;
        dst[j + 1] = *(uint4*)&p1;
    }
}

// ============================================================================
// Routing + dense tile table. tbl[i] = {e, mbase, off0, ne}; padded with zeros.
// ============================================================================
__global__ void route_kernel(const int* __restrict__ eidx,
                             int4* __restrict__ tbl,
                             int* __restrict__ slot_q) {
    __shared__ int cnt[NEXP];
    __shared__ int cur[NEXP];
    const int t = threadIdx.x;
    if (t < NEXP) cnt[t] = 0;
    __syncthreads();
    for (int q = t; q < NPAIR; q += 1024) atomicAdd(&cnt[eidx[q]], 1);
    __syncthreads();
    if (t == 0) {
        int s = 0, nt = 0;
        for (int e = 0; e < NEXP; e++) {
            cur[e] = s;
            for (int mb = 0; mb < cnt[e]; mb += 128)
                tbl[nt++] = int4{e, mb, s, cnt[e]};
            s += cnt[e];
        }
        for (; nt < MAXTILE; nt++) tbl[nt] = int4{0, 0, 0, 0};
    }
    __syncthreads();
    for (int q = t; q < NPAIR; q += 1024) {
        int e = eidx[q];
        int pos = atomicAdd(&cur[e], 1);
        slot_q[pos] = q;
    }
}

// ============================================================================
// GEMM1 + SwiGLU: BK=64, 32KB LDS, global_load_lds staging, XOR-8 swizzle.
// Tile: 128(M) x 64(N per w1/w3 half). grid: (IDIM/64, MAXTILE).
// LDS rows are 64 bf16 = 8 chunks of 16B; LDS chunk p of row r holds global
// chunk p ^ (r&7)  -> fragment ds_read_b128 lands 2-way per bank (free).
// ============================================================================
__launch_bounds__(256)
__global__ void gemm1_swiglu(const unsigned short* __restrict__ xb,
                             const unsigned short* __restrict__ w13b,
                             const int4* __restrict__ tbl,
                             const int* __restrict__ slot_q,
                             unsigned short* __restrict__ pbuf) {
    const int4 tt = tbl[blockIdx.y];
    const int e = tt.x, mbase = tt.y, off0 = tt.z, ne = tt.w;
    if (mbase >= ne) return;
    const int n0 = blockIdx.x * 64;

    __shared__ __align__(16) unsigned short As[128 * 64];
    __shared__ __align__(16) unsigned short Bs[128 * 64];

    const int t    = threadIdx.x;
    const int lane = t & 63;
    const int wid  = t >> 6;

    // staging: issue c (0..3) covers rows [c*32, c*32+32); thread's row-in-issue
    // rr = t>>3, dest chunk p = t&7, source chunk g = p ^ (row&7) = p ^ (rr&7)
    const int rr = t >> 3;
    const int g  = (t & 7) ^ (rr & 7);
    const unsigned short* pA[4];
    const unsigned short* pB[4];
    const unsigned short* wb1 = w13b + (size_t)e * (2 * IDIM) * DDIM;
    #pragma unroll
    for (int c = 0; c < 4; c++) {
        int row = c * 32 + rr;                      // 0..127
        int sl = mbase + row; if (sl > ne - 1) sl = ne - 1;
        pA[c] = xb + (size_t)(slot_q[off0 + sl] >> 1) * DDIM + g * 8;
        int wrow = (row < 64) ? (n0 + row) : (IDIM + n0 + (row - 64));  // w1 | w3
        pB[c] = wb1 + (size_t)wrow * DDIM + g * 8;
    }
    unsigned short* lA = As + wid * 512;   // + c*2048
    unsigned short* lB = Bs + wid * 512;

    const int wm = wid >> 1, wn = wid & 1;
    const int quad = lane >> 4, l16 = lane & 15;
    const int rsw = l16 & 7;
    const int co0 = (quad ^ rsw) * 8;         // k-half 0 chunk offset (shorts)
    const int co1 = ((quad + 4) ^ rsw) * 8;   // k-half 1

    floatx4 acc1[4][2], acc3[4][2];
    #pragma unroll
    for (int i = 0; i < 4; i++)
        #pragma unroll
        for (int j = 0; j < 2; j++) {
            acc1[i][j] = floatx4{0.f, 0.f, 0.f, 0.f};
            acc3[i][j] = floatx4{0.f, 0.f, 0.f, 0.f};
        }

    for (int it = 0; it < DDIM / 64; ++it) {
        const int ko = it * 64;
        __syncthreads();
        #pragma unroll
        for (int c = 0; c < 4; c++) {
            gload_lds16(pA[c] + ko, lA + c * 2048);
            gload_lds16(pB[c] + ko, lB + c * 2048);
        }
        __syncthreads();

        #pragma unroll
        for (int h = 0; h < 2; ++h) {
            const int co = h ? co1 : co0;
            short8 af[4], b1f[2], b3f[2];
            #pragma unroll
            for (int mi = 0; mi < 4; mi++)
                af[mi] = *(short8*)&As[(wm * 64 + mi * 16 + l16) * 64 + co];
            #pragma unroll
            for (int ni = 0; ni < 2; ni++) {
                b1f[ni] = *(short8*)&Bs[(wn * 32 + ni * 16 + l16) * 64 + co];
                b3f[ni] = *(short8*)&Bs[(64 + wn * 32 + ni * 16 + l16) * 64 + co];
            }
            #pragma unroll
            for (int mi = 0; mi < 4; mi++)
                #pragma unroll
                for (int ni = 0; ni < 2; ni++) {
                    acc1[mi][ni] = __builtin_amdgcn_mfma_f32_16x16x32_bf16(af[mi], b1f[ni], acc1[mi][ni], 0, 0, 0);
                    acc3[mi][ni] = __builtin_amdgcn_mfma_f32_16x16x32_bf16(af[mi], b3f[ni], acc3[mi][ni], 0, 0, 0);
                }
        }
    }

    #pragma unroll
    for (int mi = 0; mi < 4; mi++) {
        #pragma unroll
        for (int ni = 0; ni < 2; ni++) {
            const int col = n0 + wn * 32 + ni * 16 + l16;
            #pragma unroll
            for (int rw = 0; rw < 4; rw++) {
                const int s2 = mbase + wm * 64 + mi * 16 + quad * 4 + rw;
                if (s2 < ne) {
                    float v1 = acc1[mi][ni][rw];
                    float v3 = acc3[mi][ni][rw];
                    float pv = v1 / (1.f + __expf(-v1)) * v3;
                    __hip_bfloat16 pb = __float2bfloat16(pv);
                    pbuf[(size_t)(off0 + s2) * IDIM + col] = *(unsigned short*)&pb;
                }
            }
        }
    }
}

// ============================================================================
// GEMM2: BK=64, K-split x4, no atomics — each ks stores to its own partial.
// Tile: 128(M) x 128(N). grid: (DDIM/128, MAXTILE, KSPLIT).
// ============================================================================
__launch_bounds__(256)
__global__ void gemm2_scatter(const unsigned short* __restrict__ pbuf,
                              const unsigned short* __restrict__ w2b,
                              const int4* __restrict__ tbl,
                              const int* __restrict__ slot_q,
                              float* __restrict__ parts) {
    const int4 tt = tbl[blockIdx.y];
    const int e = tt.x, mbase = tt.y, off0 = tt.z, ne = tt.w;
    if (mbase >= ne) return;
    const int n0 = blockIdx.x * 128;
    const int kbase = blockIdx.z * (IDIM / KSPLIT);   // 0,512,1024,1536
    float* dstbase = parts + (size_t)blockIdx.z * NPAIR * DDIM;

    __shared__ __align__(16) unsigned short As[128 * 64];
    __shared__ __align__(16) unsigned short Bs[128 * 64];

    const int t    = threadIdx.x;
    const int lane = t & 63;
    const int wid  = t >> 6;

    const int rr = t >> 3;
    const int g  = (t & 7) ^ (rr & 7);
    const unsigned short* pA[4];
    const unsigned short* pB[4];
    const unsigned short* wb = w2b + (size_t)e * DDIM * IDIM;
    #pragma unroll
    for (int c = 0; c < 4; c++) {
        int row = c * 32 + rr;
        int sl = mbase + row; if (sl > ne - 1) sl = ne - 1;
        pA[c] = pbuf + (size_t)(off0 + sl) * IDIM + kbase + g * 8;
        pB[c] = wb + (size_t)(n0 + row) * IDIM + kbase + g * 8;
    }
    unsigned short* lA = As + wid * 512;
    unsigned short* lB = Bs + wid * 512;

    const int wm = wid >> 1, wn = wid & 1;
    const int quad = lane >> 4, l16 = lane & 15;
    const int rsw = l16 & 7;
    const int co0 = (quad ^ rsw) * 8;
    const int co1 = ((quad + 4) ^ rsw) * 8;

    floatx4 acc[4][4];
    #pragma unroll
    for (int i = 0; i < 4; i++)
        #pragma unroll
        for (int j = 0; j < 4; j++) acc[i][j] = floatx4{0.f, 0.f, 0.f, 0.f};

    for (int it = 0; it < (IDIM / KSPLIT) / 64; ++it) {   // 8 iters
        const int ko = it * 64;
        __syncthreads();
        #pragma unroll
        for (int c = 0; c < 4; c++) {
            gload_lds16(pA[c] + ko, lA + c * 2048);
            gload_lds16(pB[c] + ko, lB + c * 2048);
        }
        __syncthreads();

        #pragma unroll
        for (int h = 0; h < 2; ++h) {
            const int co = h ? co1 : co0;
            short8 af[4], bf[4];
            #pragma unroll
            for (int mi = 0; mi < 4; mi++)
                af[mi] = *(short8*)&As[(wm * 64 + mi * 16 + l16) * 64 + co];
            #pragma unroll
            for (int ni = 0; ni < 4; ni++)
                bf[ni] = *(short8*)&Bs[(wn * 64 + ni * 16 + l16) * 64 + co];
            #pragma unroll
            for (int mi = 0; mi < 4; mi++)
                #pragma unroll
                for (int ni = 0; ni < 4; ni++)
                    acc[mi][ni] = __builtin_amdgcn_mfma_f32_16x16x32_bf16(af[mi], bf[ni], acc[mi][ni], 0, 0, 0);
        }
    }

    #pragma unroll
    for (int mi = 0; mi < 4; mi++) {
        #pragma unroll
        for (int rw = 0; rw < 4; rw++) {
            const int s2 = mbase + wm * 64 + mi * 16 + quad * 4 + rw;
            if (s2 < ne) {
                const int qq = slot_q[off0 + s2];
                float* orow = dstbase + (size_t)qq * DDIM;
                #pragma unroll
                for (int ni = 0; ni < 4; ni++)
                    orow[n0 + wn * 64 + ni * 16 + l16] = acc[mi][ni][rw];
            }
        }
    }
}

// ============================================================================
// out = p0 + p1 + p2 + p3   (80 MB traffic)
// ============================================================================
__global__ void reduce_add4(float4* __restrict__ out, const float4* __restrict__ parts) {
    const int i = blockIdx.x * 256 + threadIdx.x;
    const int stride = NPAIR * DDIM / 4;
    float4 a = parts[i], b = parts[i + stride];
    float4 c = parts[i + 2 * stride], d = parts[i + 3 * stride];
    out[i] = float4{a.x + b.x + c.x + d.x, a.y + b.y + c.y + d.y,
                    a.z + b.z + c.z + d.z, a.w + b.w + c.w + d.w};
}

// ============================================================================
extern "C" void kernel_launch(void* const* d_in, const int* in_sizes, int n_in,
                              void* d_out, int out_size, void* d_ws, size_t ws_size,
                              hipStream_t stream) {
    const float* x    = (const float*)d_in[0];
    const float* w13  = (const float*)d_in[1];
    const float* w2   = (const float*)d_in[2];
    const int*   eidx = (const int*)d_in[3];
    float* out = (float*)d_out;

    // ws layout (NEED = 121,700,352 B — confirmed available in R3/R4):
    //   [128,768) tile tbl; [1024,17408) slot_q; [OFF_XB,+4MB) xb;
    //   [OFF_W13B,+64MB) w13b (dead after gemm1 -> reused as 4x16MB partials);
    //   [OFF_W2B,+32MB) w2b; [OFF_PBUF,+16MB) pbuf
    const size_t OFF_XB   = 65536;
    const size_t OFF_W13B = OFF_XB + (size_t)4 * 1024 * 1024;
    const size_t OFF_W2B  = OFF_W13B + (size_t)64 * 1024 * 1024;
    const size_t OFF_PBUF = OFF_W2B + (size_t)32 * 1024 * 1024;

    int4* tbl   = (int4*)((char*)d_ws + 128);
    int* slot_q = (int*)((char*)d_ws + 1024);
    unsigned short* xb   = (unsigned short*)((char*)d_ws + OFF_XB);
    unsigned short* w13b = (unsigned short*)((char*)d_ws + OFF_W13B);
    unsigned short* w2b  = (unsigned short*)((char*)d_ws + OFF_W2B);
    unsigned short* pbuf = (unsigned short*)((char*)d_ws + OFF_PBUF);
    float* parts = (float*)((char*)d_ws + OFF_W13B);   // 64 MB, 4 partials

    hipLaunchKernelGGL(route_kernel, dim3(1), dim3(1024), 0, stream, eidx, tbl, slot_q);
    hipLaunchKernelGGL(cvt_all, dim3(2048), dim3(256), 0, stream,
                       (const fvec4*)x, (const fvec4*)w13, (const fvec4*)w2,
                       (uint4*)xb, (uint4*)w13b, (uint4*)w2b);
    hipLaunchKernelGGL(gemm1_swiglu, dim3(IDIM / 64, MAXTILE), dim3(256), 0, stream,
                       xb, w13b, tbl, slot_q, pbuf);
    hipLaunchKernelGGL(gemm2_scatter, dim3(DDIM / 128, MAXTILE, KSPLIT), dim3(256), 0, stream,
                       pbuf, w2b, tbl, slot_q, parts);
    hipLaunchKernelGGL(reduce_add4, dim3((NPAIR * DDIM / 4) / 256), dim3(256), 0, stream,
                       (float4*)out, (const float4*)parts);
}